// Round 6
// baseline (110.658 us; speedup 1.0000x reference)
//
#include <hip/hip_runtime.h>
#include <stdint.h>

#define NBITS 57
#define RPB   256   // rows per block

__global__ __launch_bounds__(256) void lzc57_kernel(const uint32_t* __restrict__ X,
                                                    float* __restrict__ out,
                                                    int nrows) {
    __shared__ float s_out[RPB * 6];   // 6144 B (output coalescing only)
    const int tid  = threadIdx.x;
    const int row0 = blockIdx.x * RPB;
    const int row  = row0 + tid;
    const int rows = min(RPB, nrows - row0);

    if (row < nrows) {
        // 16B-aligned 240B window covering this row's 228B (offset = row&3 dwords)
        const size_t wbase = ((size_t)row * NBITS) & ~(size_t)3;
        const uint4* p = (const uint4*)(X + wbase);

        uint4 d[15];
        #pragma unroll
        for (int i = 0; i < 15; ++i) d[i] = p[i];   // 15 independent dwordx4 in flight

        uint32_t w[60];
        #pragma unroll
        for (int i = 0; i < 15; ++i) {
            w[4*i+0] = d[i].x; w[4*i+1] = d[i].y;
            w[4*i+2] = d[i].z; w[4*i+3] = d[i].w;
        }
        // words are exactly 0x3F800000 (1.0f) or 0x00000000: bit 29 discriminates
        uint32_t mlo = 0u, mhi = 0u;
        #pragma unroll
        for (int j = 0; j < 32; ++j)
            mlo |= ((w[j] >> 29) & 1u) << j;
        #pragma unroll
        for (int j = 32; j < 60; ++j)
            mhi |= ((w[j] >> 29) & 1u) << (j - 32);

        const uint64_t m = ((uint64_t)mhi << 32) | mlo;
        const uint64_t v = (m >> (row & 3)) & ((1ull << NBITS) - 1ull);
        const int lzc = v ? (__ffsll((unsigned long long)v) - 1) : NBITS;

        #pragma unroll
        for (int j = 0; j < 6; ++j)
            s_out[tid * 6 + j] = (float)((lzc >> (5 - j)) & 1);
    }
    __syncthreads();

    // ---- coalesced float4 store of staged output ----
    float* dstf = out + (size_t)row0 * 6;
    const int nout = rows * 6;
    const int no4 = nout >> 2;
    const float4* s4 = (const float4*)s_out;
    float4* o4 = (float4*)dstf;
    for (int i = tid; i < no4; i += RPB) o4[i] = s4[i];
    for (int i = (no4 << 2) + tid; i < nout; i += RPB) dstf[i] = s_out[i];
}

extern "C" void kernel_launch(void* const* d_in, const int* in_sizes, int n_in,
                              void* d_out, int out_size, void* d_ws, size_t ws_size,
                              hipStream_t stream) {
    const uint32_t* X = (const uint32_t*)d_in[0];
    float* out = (float*)d_out;
    const int nrows = in_sizes[0] / NBITS;
    const int blocks = (nrows + RPB - 1) / RPB;
    lzc57_kernel<<<blocks, RPB, 0, stream>>>(X, out, nrows);
}

// Round 7
// 100.970 us; speedup vs baseline: 1.0960x; 1.0960x over previous
//
#include <hip/hip_runtime.h>
#include <stdint.h>

#define NBITS 57
#define RPB   256   // rows per block; full block = 14592 words = 3648 uint4 = 57 wave-rounds

__global__ __launch_bounds__(256) void lzc57_kernel(const uint32_t* __restrict__ X,
                                                    float* __restrict__ out,
                                                    int nrows) {
    __shared__ unsigned long long s_mask[230];        // 228 word-masks (+guard), 1840 B
    __shared__ __align__(16) float s_out[RPB * 6];    // 6144 B
    const int tid  = threadIdx.x;
    const int wave = tid >> 6;
    const int lane = tid & 63;
    const int row0 = blockIdx.x * RPB;
    const int rows = min(RPB, nrows - row0);

    if (rows == RPB) {
        const uint4* src4 = (const uint4*)(X + (size_t)row0 * NBITS);

        // ---- load phase: wave w takes rounds r = w + 4i (wave0: 15, else 14) ----
        uint4 d[15];
        #pragma unroll
        for (int i = 0; i < 15; ++i)
            if (i < 14 || wave == 0)
                d[i] = src4[(wave + 4 * i) * 64 + lane];   // coalesced 1KB/wave/instr

        // ---- transpose phase: nibble -> swizzle XOR tree -> u64 mask per 64 words ----
        #pragma unroll
        for (int i = 0; i < 15; ++i) {
            if (i < 14 || wave == 0) {
                const int r = wave + 4 * i;
                // bit29 discriminates 0x3F800000 vs 0; bit c = word 256r+4*lane+c
                uint32_t n = ((d[i].x >> 29) & 1u) | ((d[i].y >> 28) & 2u)
                           | ((d[i].z >> 27) & 4u) | ((d[i].w >> 26) & 8u);
                // combine lanes: after step s, lanes ≡0 mod 2^(s+1) hold 4*2^(s+1) bits
                n |= (uint32_t)__builtin_amdgcn_ds_swizzle((int)n, 0x041F) << 4;   // xor 1
                n |= (uint32_t)__builtin_amdgcn_ds_swizzle((int)n, 0x081F) << 8;   // xor 2
                n |= (uint32_t)__builtin_amdgcn_ds_swizzle((int)n, 0x101F) << 16;  // xor 4
                const uint32_t hi = (uint32_t)__builtin_amdgcn_ds_swizzle((int)n, 0x201F); // xor 8
                if ((lane & 15) == 0)   // lanes 0,16,32,48: words [256r+4*lane .. +63]
                    s_mask[4 * r + (lane >> 4)] = ((unsigned long long)hi << 32) | n;
            }
        }
    }
    __syncthreads();

    if (rows == RPB) {
        // ---- per-row LZC via 57-bit funnel extract ----
        const int bitpos = tid * NBITS;
        const int m = bitpos >> 6;
        const int s = bitpos & 63;
        const unsigned long long lo = s_mask[m];
        const unsigned long long hi = s_mask[m + 1];   // guard entry; masked off when s<8
        unsigned long long v = s ? ((lo >> s) | (hi << (64 - s))) : lo;
        v &= (1ull << NBITS) - 1ull;
        const int lzc = v ? (__ffsll(v) - 1) : NBITS;
        #pragma unroll
        for (int j = 0; j < 6; ++j)
            s_out[tid * 6 + j] = (float)((lzc >> (5 - j)) & 1);
    } else if (tid < rows) {
        // partial last block (128 rows): direct scalar per-row path, runs once per grid
        const uint32_t* rw = X + (size_t)(row0 + tid) * NBITS;
        uint32_t mlo = 0u, mhi = 0u;
        #pragma unroll
        for (int i = 0; i < 32; ++i) mlo |= ((rw[i] >> 29) & 1u) << i;
        #pragma unroll
        for (int i = 32; i < NBITS; ++i) mhi |= ((rw[i] >> 29) & 1u) << (i - 32);
        const int lzc = mlo ? (__ffs(mlo) - 1) : (mhi ? (31 + __ffs(mhi)) : NBITS);
        #pragma unroll
        for (int j = 0; j < 6; ++j)
            s_out[tid * 6 + j] = (float)((lzc >> (5 - j)) & 1);
    }
    __syncthreads();

    // ---- coalesced float4 store of staged output ----
    float* dstf = out + (size_t)row0 * 6;
    const int nout = rows * 6;
    const int no4 = nout >> 2;
    const float4* s4 = (const float4*)s_out;
    float4* o4 = (float4*)dstf;
    for (int i = tid; i < no4; i += RPB) o4[i] = s4[i];
    for (int i = (no4 << 2) + tid; i < nout; i += RPB) dstf[i] = s_out[i];
}

extern "C" void kernel_launch(void* const* d_in, const int* in_sizes, int n_in,
                              void* d_out, int out_size, void* d_ws, size_t ws_size,
                              hipStream_t stream) {
    const uint32_t* X = (const uint32_t*)d_in[0];
    float* out = (float*)d_out;
    const int nrows = in_sizes[0] / NBITS;
    const int blocks = (nrows + RPB - 1) / RPB;
    lzc57_kernel<<<blocks, RPB, 0, stream>>>(X, out, nrows);
}

// Round 8
// 80.141 us; speedup vs baseline: 1.3808x; 1.2599x over previous
//
#include <hip/hip_runtime.h>
#include <stdint.h>

#define NBITS 57
#define RPB   256

__global__ __launch_bounds__(256) void lzc57_kernel(const uint32_t* __restrict__ X,
                                                    float* __restrict__ out,
                                                    int nrows) {
    __shared__ __align__(16) float s_out[RPB * 6];   // 6144 B (output coalescing only)
    const int tid  = threadIdx.x;
    const int row0 = blockIdx.x * RPB;
    const int row  = row0 + tid;
    const int rows = min(RPB, nrows - row0);

    if (row < nrows) {
        const size_t w0 = (size_t)row * NBITS;   // row's first word index
        const size_t wb = w0 & ~(size_t)3;       // 16B-aligned window base
        const int shift = (int)(w0 - wb);        // 0..3 (words of previous row's tail)
        const uint4* p = (const uint4*)(X + wb);

        // one 64B window: 4 independent dwordx4 (2 cache lines per row)
        uint4 d[4];
        #pragma unroll
        for (int i = 0; i < 4; ++i) d[i] = p[i];

        uint32_t w[16];
        #pragma unroll
        for (int i = 0; i < 4; ++i) {
            w[4*i+0] = d[i].x; w[4*i+1] = d[i].y;
            w[4*i+2] = d[i].z; w[4*i+3] = d[i].w;
        }
        // words are exactly 0x3F800000 (1.0f) or 0: bit 29 discriminates
        uint32_t m = 0u;
        #pragma unroll
        for (int k = 0; k < 16; ++k)
            m |= ((w[k] >> 29) & 1u) << k;
        m >>= shift;   // bit j = row word j, valid for j < 16-shift; high bits zero-filled

        int lzc;
        if (m) {
            lzc = __ffs(m) - 1;                  // hot path: first 1 within 13..16 bits
        } else {
            // cold path (~1e-4 of rows): full 57-word scalar read
            const uint32_t* rw = X + w0;
            uint32_t mlo = 0u, mhi = 0u;
            #pragma unroll
            for (int i = 0; i < 32; ++i)
                mlo |= ((rw[i] >> 29) & 1u) << i;
            #pragma unroll
            for (int i = 32; i < NBITS; ++i)
                mhi |= ((rw[i] >> 29) & 1u) << (i - 32);
            lzc = mlo ? (__ffs(mlo) - 1) : (mhi ? (31 + __ffs(mhi)) : NBITS);
        }

        #pragma unroll
        for (int j = 0; j < 6; ++j)
            s_out[tid * 6 + j] = (float)((lzc >> (5 - j)) & 1);
    }
    __syncthreads();

    // ---- coalesced float4 store of staged output ----
    float* dstf = out + (size_t)row0 * 6;
    const int nout = rows * 6;
    const int no4 = nout >> 2;
    const float4* s4 = (const float4*)s_out;
    float4* o4 = (float4*)dstf;
    for (int i = tid; i < no4; i += RPB) o4[i] = s4[i];
    for (int i = (no4 << 2) + tid; i < nout; i += RPB) dstf[i] = s_out[i];
}

extern "C" void kernel_launch(void* const* d_in, const int* in_sizes, int n_in,
                              void* d_out, int out_size, void* d_ws, size_t ws_size,
                              hipStream_t stream) {
    const uint32_t* X = (const uint32_t*)d_in[0];
    float* out = (float*)d_out;
    const int nrows = in_sizes[0] / NBITS;
    const int blocks = (nrows + RPB - 1) / RPB;
    lzc57_kernel<<<blocks, RPB, 0, stream>>>(X, out, nrows);
}

// Round 9
// 51.498 us; speedup vs baseline: 2.1488x; 1.5562x over previous
//
#include <hip/hip_runtime.h>
#include <stdint.h>

#define NBITS 57
#define RPB   256

__global__ __launch_bounds__(256) void lzc57_kernel(const uint32_t* __restrict__ X,
                                                    float* __restrict__ out,
                                                    int nrows) {
    __shared__ __align__(16) float s_out[RPB * 6];   // 6144 B (output coalescing only)
    const int tid  = threadIdx.x;
    const int row0 = blockIdx.x * RPB;
    const int row  = row0 + tid;
    const int rows = min(RPB, nrows - row0);

    if (row < nrows) {
        const size_t w0 = (size_t)row * NBITS;        // row's first word index
        const size_t lw = w0 & ~(size_t)31;           // 128B line base (words)
        const int off   = (int)(w0 - lw);             // 0..31
        // 64B window clamped to stay inside this row's head 128B line:
        //   off<=19: 16B-aligned at w0  -> start=off&3, checks >=13 words
        //   off>=20: snapped to line+64 -> start=off-16, checks 32-off words
        const int wb_off = (off <= 19) ? (off & ~3) : 16;   // window base within line (words)
        const int start  = off - wb_off;                    // row word 0 position in window
        const uint4* p = (const uint4*)(X + lw + wb_off);

        uint4 d[4];
        #pragma unroll
        for (int i = 0; i < 4; ++i) d[i] = p[i];      // 4 dwordx4, all in ONE 128B line

        uint32_t w[16];
        #pragma unroll
        for (int i = 0; i < 4; ++i) {
            w[4*i+0] = d[i].x; w[4*i+1] = d[i].y;
            w[4*i+2] = d[i].z; w[4*i+3] = d[i].w;
        }
        // words are exactly 0x3F800000 (1.0f) or 0: bit 29 discriminates
        uint32_t m = 0u;
        #pragma unroll
        for (int k = 0; k < 16; ++k)
            m |= ((w[k] >> 29) & 1u) << k;
        const uint32_t vm = m >> start;   // bit j = row word j; prev-row bits shifted out

        int lzc;
        if (vm) {
            lzc = __ffs(vm) - 1;          // hot path: first 1 within the head line
        } else {
            // cold path (~3% of rows): full 57-word scalar scan
            const uint32_t* rw = X + w0;
            uint32_t mlo = 0u, mhi = 0u;
            #pragma unroll
            for (int i = 0; i < 32; ++i)
                mlo |= ((rw[i] >> 29) & 1u) << i;
            #pragma unroll
            for (int i = 32; i < NBITS; ++i)
                mhi |= ((rw[i] >> 29) & 1u) << (i - 32);
            lzc = mlo ? (__ffs(mlo) - 1) : (mhi ? (31 + __ffs(mhi)) : NBITS);
        }

        #pragma unroll
        for (int j = 0; j < 6; ++j)
            s_out[tid * 6 + j] = (float)((lzc >> (5 - j)) & 1);
    }
    __syncthreads();

    // ---- coalesced float4 store of staged output ----
    float* dstf = out + (size_t)row0 * 6;
    const int nout = rows * 6;
    const int no4 = nout >> 2;
    const float4* s4 = (const float4*)s_out;
    float4* o4 = (float4*)dstf;
    for (int i = tid; i < no4; i += RPB) o4[i] = s4[i];
    for (int i = (no4 << 2) + tid; i < nout; i += RPB) dstf[i] = s_out[i];
}

extern "C" void kernel_launch(void* const* d_in, const int* in_sizes, int n_in,
                              void* d_out, int out_size, void* d_ws, size_t ws_size,
                              hipStream_t stream) {
    const uint32_t* X = (const uint32_t*)d_in[0];
    float* out = (float*)d_out;
    const int nrows = in_sizes[0] / NBITS;
    const int blocks = (nrows + RPB - 1) / RPB;
    lzc57_kernel<<<blocks, RPB, 0, stream>>>(X, out, nrows);
}